// Round 2
// baseline (4022.477 us; speedup 1.0000x reference)
//
#include <hip/hip_runtime.h>

typedef unsigned short u16;
typedef short v8s __attribute__((ext_vector_type(8)));
typedef float v4f __attribute__((ext_vector_type(4)));

// T=256, B=64, NIN=H=512, NOUT=512, 4H=2048, T*B=16384
#define TT 256
#define BB 64
#define HH 512
#define G4 2048
#define MTB 16384

static __device__ __forceinline__ float bf2f(u16 u) {
    unsigned int x = ((unsigned int)u) << 16;
    union { unsigned int i; float f; } c; c.i = x; return c.f;
}
static __device__ __forceinline__ u16 f2bf(float f) {
    union { float f; unsigned int i; } c; c.f = f;
    unsigned int u = c.i;
    u += 0x7fffu + ((u >> 16) & 1u);   // RNE
    return (u16)(u >> 16);
}

__global__ __launch_bounds__(256) void cvt_bf16(const float* __restrict__ src,
                                                u16* __restrict__ dst, int n) {
    int i = blockIdx.x * blockDim.x + threadIdx.x;
    int stride = gridDim.x * blockDim.x;
    for (int j = i * 4; j < n; j += stride * 4) {
        float4 v = *reinterpret_cast<const float4*>(src + j);
        ushort4 o;
        o.x = f2bf(v.x); o.y = f2bf(v.y); o.z = f2bf(v.z); o.w = f2bf(v.w);
        *reinterpret_cast<ushort4*>(dst + j) = o;
    }
}

// C[M][N] = A[M][K] * B[N][K]^T (+ bias).  A,B bf16 K-contiguous; 128x128 tile, BK=64,
// 4 waves in 2x2, each wave 64x64 = 4x4 16x16x32 fragments. M,N,K multiples of 128 assumed.
template<bool OUT_BF16, bool BIAS_M>
__global__ __launch_bounds__(256) void gemm_bt(const u16* __restrict__ A,
                                               const u16* __restrict__ Bm,
                                               void* __restrict__ Cv,
                                               const float* __restrict__ bias1,
                                               const float* __restrict__ bias2,
                                               int M, int N, int K) {
    __shared__ u16 lds_a[128 * 64];
    __shared__ u16 lds_b[128 * 64];
    const int tid = threadIdx.x, lane = tid & 63;
    const int m0 = blockIdx.y * 128, n0 = blockIdx.x * 128;
    const int wid = tid >> 6, wm = wid >> 1, wn = wid & 1;
    v4f acc[4][4] = {};

    const int srow  = tid >> 3;        // 0..31: row within 32-row staging stripe
    const int skoff = (tid & 7) * 8;   // bf16 elements within 64-wide k
    const u16* Ag = A + (size_t)(m0 + srow) * K + skoff;
    const u16* Bg = Bm + (size_t)(n0 + srow) * K + skoff;
    u16* la = lds_a + srow * 64 + skoff;
    u16* lb = lds_b + srow * 64 + skoff;

    for (int k0 = 0; k0 < K; k0 += 64) {
        #pragma unroll
        for (int q = 0; q < 4; ++q) {
            *reinterpret_cast<v8s*>(la + q * 32 * 64) =
                *reinterpret_cast<const v8s*>(Ag + (size_t)q * 32 * K + k0);
            *reinterpret_cast<v8s*>(lb + q * 32 * 64) =
                *reinterpret_cast<const v8s*>(Bg + (size_t)q * 32 * K + k0);
        }
        __syncthreads();
        #pragma unroll
        for (int kk = 0; kk < 2; ++kk) {
            v8s af[4], bfr[4];
            #pragma unroll
            for (int i = 0; i < 4; ++i)
                af[i] = *reinterpret_cast<const v8s*>(
                    lds_a + (wm * 64 + i * 16 + (lane & 15)) * 64 + kk * 32 + (lane >> 4) * 8);
            #pragma unroll
            for (int i = 0; i < 4; ++i)
                bfr[i] = *reinterpret_cast<const v8s*>(
                    lds_b + (wn * 64 + i * 16 + (lane & 15)) * 64 + kk * 32 + (lane >> 4) * 8);
            #pragma unroll
            for (int i = 0; i < 4; ++i)
                #pragma unroll
                for (int j = 0; j < 4; ++j)
                    acc[i][j] = __builtin_amdgcn_mfma_f32_16x16x32_bf16(af[i], bfr[j], acc[i][j], 0, 0, 0);
        }
        __syncthreads();
    }
    // epilogue: D col = lane&15 (n), row = (lane>>4)*4 + reg (m)
    #pragma unroll
    for (int i = 0; i < 4; ++i) {
        #pragma unroll
        for (int j = 0; j < 4; ++j) {
            #pragma unroll
            for (int r = 0; r < 4; ++r) {
                int m = m0 + wm * 64 + i * 16 + (lane >> 4) * 4 + r;
                int n = n0 + wn * 64 + j * 16 + (lane & 15);
                float v = acc[i][j][r];
                if (BIAS_M) { v += bias1[m]; if (bias2) v += bias2[m]; }
                else        { v += bias1[n]; }
                if (OUT_BF16) ((u16*)Cv)[(size_t)m * N + n] = f2bf(v);
                else          ((float*)Cv)[(size_t)m * N + n] = v;
            }
        }
    }
}

static __device__ __forceinline__ float sigm(float x) { return 1.f / (1.f + __expf(-x)); }
static __device__ __forceinline__ float tanh_(float x) { return 2.f / (1.f + __expf(-2.f * x)) - 1.f; }

// Persistent bidirectional LSTM recurrence. 64 blocks: blockIdx.x>>5 = dir, &31 = cg
// (16-column group of j). 4 waves/block; wave nf covers batch cols b = nf*16..+15,
// ALL 4 gates (A-fragments for 4 gates preloaded into 256 VGPRs; b-fragment shared
// across the 4 gate MFMAs). (i,f,g,o) for a (jj,b) land in the same lane -> no LDS
// exchange; c lives in 4 regs/lane. Software barrier per dir across its 32 blocks.
__global__ __launch_bounds__(256, 1) void lstm_persist(
    const u16* __restrict__ w_hh,        // [2][2048][512]
    const u16* __restrict__ xgT,         // [2][2048][16384]  col index = t*64+b
    u16* __restrict__ h_all,             // [256*64][1024]
    unsigned* __restrict__ bar)          // [2*32] counters, 128B apart
{
    __shared__ u16 lds_h[64 * 520];      // h_prev staged, pad 512->520 (bank decorrelate)
    const int bx = blockIdx.x;
    const int d = bx >> 5, cg = bx & 31;
    const int tid = threadIdx.x;
    const int lane = tid & 63, nf = tid >> 6;
    const int lrow = lane & 15, lk = lane >> 4;

    // ---- preload A fragments: a[G][kk], row = G*512 + cg*16 + lrow ----
    v8s a[4][16];
    #pragma unroll
    for (int G = 0; G < 4; ++G) {
        const u16* wrow = w_hh + ((size_t)d * G4 + G * HH + cg * 16 + lrow) * HH + lk * 8;
        #pragma unroll
        for (int kk = 0; kk < 16; ++kk)
            a[G][kk] = *reinterpret_cast<const v8s*>(wrow + kk * 32);
    }

    float c[4] = {0.f, 0.f, 0.f, 0.f};
    const int b = nf * 16 + lrow;        // this lane's batch column
    unsigned* cnt = bar + d * 32;        // per-dir counter, separate cache lines

    for (int s = 0; s < TT; ++s) {
        const int t = d ? (TT - 1 - s) : s;
        v4f acc[4] = {};                 // one 16x16 fragment per gate
        if (s > 0) {
            const int tprev = d ? (t + 1) : (t - 1);
            // stage h[tprev] dir-slice (64 rows x 512) into LDS, coalesced
            const u16* hsrc = h_all + (size_t)tprev * BB * 1024 + d * HH;
            #pragma unroll
            for (int q = 0; q < 16; ++q) {
                int flat = q * 256 + tid;
                int row = flat >> 6, c8 = flat & 63;
                *reinterpret_cast<v8s*>(&lds_h[row * 520 + c8 * 8]) =
                    *reinterpret_cast<const v8s*>(hsrc + (size_t)row * 1024 + c8 * 8);
            }
            __syncthreads();
            #pragma unroll
            for (int kk = 0; kk < 16; ++kk) {
                v8s bfrag = *reinterpret_cast<const v8s*>(
                    &lds_h[b * 520 + kk * 32 + lk * 8]);
                #pragma unroll
                for (int G = 0; G < 4; ++G)
                    acc[G] = __builtin_amdgcn_mfma_f32_16x16x32_bf16(a[G][kk], bfrag, acc[G], 0, 0, 0);
            }
        }
        // gates + state update; xg row = G*512 + cg*16 + jj, col = t*64 + b
        const u16* xgb = xgT + (size_t)d * G4 * MTB + (size_t)t * BB + b;
        ushort4 hout;
        #pragma unroll
        for (int r = 0; r < 4; ++r) {
            size_t rbase = (size_t)(cg * 16 + lk * 4 + r) * MTB;
            float pi = acc[0][r] + bf2f(xgb[rbase]);
            float pf = acc[1][r] + bf2f(xgb[rbase + (size_t)HH * MTB]);
            float pg = acc[2][r] + bf2f(xgb[rbase + (size_t)2 * HH * MTB]);
            float po = acc[3][r] + bf2f(xgb[rbase + (size_t)3 * HH * MTB]);
            float iv = sigm(pi), fv = sigm(pf), gv = tanh_(pg), ov = sigm(po);
            float cc = fv * c[r] + iv * gv;
            c[r] = cc;
            ((u16*)&hout)[r] = f2bf(ov * tanh_(cc));
        }
        // h[t][b][d*512 + cg*16 + lk*4 .. +3]  (8B store)
        *reinterpret_cast<ushort4*>(
            h_all + ((size_t)t * BB + b) * 1024 + d * HH + cg * 16 + lk * 4) = hout;

        // ---- grid barrier among this dir's 32 blocks ----
        __syncthreads();                          // drains this block's stores (vmcnt 0)
        if (tid == 0) {
            __threadfence();                      // release: writeback XCD L2
            __hip_atomic_fetch_add(cnt, 1u, __ATOMIC_RELEASE, __HIP_MEMORY_SCOPE_AGENT);
            unsigned target = 32u * (unsigned)(s + 1);
            while (__hip_atomic_load(cnt, __ATOMIC_ACQUIRE, __HIP_MEMORY_SCOPE_AGENT) < target)
                __builtin_amdgcn_s_sleep(1);
            __threadfence();                      // acquire: invalidate L1/L2
        }
        __syncthreads();
    }
}

extern "C" void kernel_launch(void* const* d_in, const int* in_sizes, int n_in,
                              void* d_out, int out_size, void* d_ws, size_t ws_size,
                              hipStream_t stream) {
    const float* x    = (const float*)d_in[0];
    const float* wihf = (const float*)d_in[1];
    const float* whhf = (const float*)d_in[2];
    const float* bihf = (const float*)d_in[3];
    const float* bhhf = (const float*)d_in[4];
    const float* wihb = (const float*)d_in[5];
    const float* whhb = (const float*)d_in[6];
    const float* bihb = (const float*)d_in[7];
    const float* bhhb = (const float*)d_in[8];
    const float* fcw  = (const float*)d_in[9];
    const float* fcb  = (const float*)d_in[10];

    char* ws = (char*)d_ws;
    size_t off = 0;
    auto alloc = [&](size_t bytes) {
        off = (off + 255) & ~(size_t)255;
        char* p = ws + off; off += bytes; return p;
    };
    u16* x_bf    = (u16*)alloc((size_t)MTB * 512 * 2);        // 16.8 MB
    u16* wih_bf  = (u16*)alloc((size_t)2 * G4 * 512 * 2);     // 4.2 MB
    u16* whh_bf  = (u16*)alloc((size_t)2 * G4 * 512 * 2);     // 4.2 MB
    u16* fcw_bf  = (u16*)alloc((size_t)512 * 1024 * 2);       // 1.0 MB
    u16* xgT     = (u16*)alloc((size_t)2 * G4 * MTB * 2);     // 134.2 MB
    u16* h_all   = (u16*)alloc((size_t)MTB * 1024 * 2);       // 33.6 MB
    unsigned* bar = (unsigned*)alloc(64 * sizeof(unsigned));  // barrier counters
    (void)ws_size;

    // ---- convert inputs to bf16 ----
    cvt_bf16<<<1024, 256, 0, stream>>>(x, x_bf, MTB * 512);
    cvt_bf16<<<256, 256, 0, stream>>>(wihf, wih_bf, G4 * 512);
    cvt_bf16<<<256, 256, 0, stream>>>(wihb, wih_bf + (size_t)G4 * 512, G4 * 512);
    cvt_bf16<<<256, 256, 0, stream>>>(whhf, whh_bf, G4 * 512);
    cvt_bf16<<<256, 256, 0, stream>>>(whhb, whh_bf + (size_t)G4 * 512, G4 * 512);
    cvt_bf16<<<128, 256, 0, stream>>>(fcw, fcw_bf, 512 * 1024);

    // ---- phase 1: xgT[d] = w_ih[d] @ x^T + (b_ih + b_hh), bf16 out, gate-major ----
    gemm_bt<true, true><<<dim3(MTB / 128, G4 / 128), 256, 0, stream>>>(
        wih_bf, x_bf, xgT, bihf, bhhf, G4, MTB, 512);
    gemm_bt<true, true><<<dim3(MTB / 128, G4 / 128), 256, 0, stream>>>(
        wih_bf + (size_t)G4 * 512, x_bf, xgT + (size_t)G4 * MTB, bihb, bhhb, G4, MTB, 512);

    // ---- phase 2: persistent recurrence, both directions, software barrier ----
    hipMemsetAsync(bar, 0, 64 * sizeof(unsigned), stream);
    lstm_persist<<<64, 256, 0, stream>>>(whh_bf, xgT, h_all, bar);

    // ---- phase 3: out = h_all @ fc_w^T + fc_b, fp32 out ----
    gemm_bt<false, false><<<dim3(512 / 128, MTB / 128), 256, 0, stream>>>(
        h_all, fcw_bf, d_out, fcb, nullptr, MTB, 512, 1024);
}

// Round 3
// 1697.398 us; speedup vs baseline: 2.3698x; 2.3698x over previous
//
#include <hip/hip_runtime.h>

typedef unsigned short u16;
typedef short v8s __attribute__((ext_vector_type(8)));
typedef float v4f __attribute__((ext_vector_type(4)));

// T=256, B=64, NIN=H=512, NOUT=512, 4H=2048, T*B=16384
#define TT 256
#define BB 64
#define HH 512
#define G4 2048
#define MTB 16384

static __device__ __forceinline__ float bf2f(u16 u) {
    unsigned int x = ((unsigned int)u) << 16;
    union { unsigned int i; float f; } c; c.i = x; return c.f;
}
static __device__ __forceinline__ u16 f2bf(float f) {
    union { float f; unsigned int i; } c; c.f = f;
    unsigned int u = c.i;
    u += 0x7fffu + ((u >> 16) & 1u);   // RNE
    return (u16)(u >> 16);
}

__global__ __launch_bounds__(256) void cvt_bf16(const float* __restrict__ src,
                                                u16* __restrict__ dst, int n) {
    int i = blockIdx.x * blockDim.x + threadIdx.x;
    int stride = gridDim.x * blockDim.x;
    for (int j = i * 4; j < n; j += stride * 4) {
        float4 v = *reinterpret_cast<const float4*>(src + j);
        ushort4 o;
        o.x = f2bf(v.x); o.y = f2bf(v.y); o.z = f2bf(v.z); o.w = f2bf(v.w);
        *reinterpret_cast<ushort4*>(dst + j) = o;
    }
}

// C[M][N] = A[M][K] * B[N][K]^T (+ bias).  A,B bf16 K-contiguous; 128x128 tile, BK=64,
// 4 waves in 2x2, each wave 64x64 = 4x4 16x16x32 fragments. M,N,K multiples of 128 assumed.
template<bool OUT_BF16, bool BIAS_M>
__global__ __launch_bounds__(256) void gemm_bt(const u16* __restrict__ A,
                                               const u16* __restrict__ Bm,
                                               void* __restrict__ Cv,
                                               const float* __restrict__ bias1,
                                               const float* __restrict__ bias2,
                                               int M, int N, int K) {
    __shared__ u16 lds_a[128 * 64];
    __shared__ u16 lds_b[128 * 64];
    const int tid = threadIdx.x, lane = tid & 63;
    const int m0 = blockIdx.y * 128, n0 = blockIdx.x * 128;
    const int wid = tid >> 6, wm = wid >> 1, wn = wid & 1;
    v4f acc[4][4] = {};

    const int srow  = tid >> 3;        // 0..31: row within 32-row staging stripe
    const int skoff = (tid & 7) * 8;   // bf16 elements within 64-wide k
    const u16* Ag = A + (size_t)(m0 + srow) * K + skoff;
    const u16* Bg = Bm + (size_t)(n0 + srow) * K + skoff;
    u16* la = lds_a + srow * 64 + skoff;
    u16* lb = lds_b + srow * 64 + skoff;

    for (int k0 = 0; k0 < K; k0 += 64) {
        #pragma unroll
        for (int q = 0; q < 4; ++q) {
            *reinterpret_cast<v8s*>(la + q * 32 * 64) =
                *reinterpret_cast<const v8s*>(Ag + (size_t)q * 32 * K + k0);
            *reinterpret_cast<v8s*>(lb + q * 32 * 64) =
                *reinterpret_cast<const v8s*>(Bg + (size_t)q * 32 * K + k0);
        }
        __syncthreads();
        #pragma unroll
        for (int kk = 0; kk < 2; ++kk) {
            v8s af[4], bfr[4];
            #pragma unroll
            for (int i = 0; i < 4; ++i)
                af[i] = *reinterpret_cast<const v8s*>(
                    lds_a + (wm * 64 + i * 16 + (lane & 15)) * 64 + kk * 32 + (lane >> 4) * 8);
            #pragma unroll
            for (int i = 0; i < 4; ++i)
                bfr[i] = *reinterpret_cast<const v8s*>(
                    lds_b + (wn * 64 + i * 16 + (lane & 15)) * 64 + kk * 32 + (lane >> 4) * 8);
            #pragma unroll
            for (int i = 0; i < 4; ++i)
                #pragma unroll
                for (int j = 0; j < 4; ++j)
                    acc[i][j] = __builtin_amdgcn_mfma_f32_16x16x32_bf16(af[i], bfr[j], acc[i][j], 0, 0, 0);
        }
        __syncthreads();
    }
    // epilogue: D col = lane&15 (n), row = (lane>>4)*4 + reg (m)
    #pragma unroll
    for (int i = 0; i < 4; ++i) {
        #pragma unroll
        for (int j = 0; j < 4; ++j) {
            #pragma unroll
            for (int r = 0; r < 4; ++r) {
                int m = m0 + wm * 64 + i * 16 + (lane >> 4) * 4 + r;
                int n = n0 + wn * 64 + j * 16 + (lane & 15);
                float v = acc[i][j][r];
                if (BIAS_M) { v += bias1[m]; if (bias2) v += bias2[m]; }
                else        { v += bias1[n]; }
                if (OUT_BF16) ((u16*)Cv)[(size_t)m * N + n] = f2bf(v);
                else          ((float*)Cv)[(size_t)m * N + n] = v;
            }
        }
    }
}

static __device__ __forceinline__ float sigm(float x) { return 1.f / (1.f + __expf(-x)); }
static __device__ __forceinline__ float tanh_(float x) { return 2.f / (1.f + __expf(-2.f * x)) - 1.f; }

// Persistent bidirectional LSTM recurrence, fence-free coherence.
// 64 blocks x 512 threads: blockIdx.x>>5 = dir d, &31 = cg (16-column group of j).
// 8 waves/block: wave = (kh, nf); kh = K-half (k in [kh*256, kh*256+256)),
// nf = batch-group (b = nf*16 + lane&15). Each wave holds a[4 gates][8 kk] = 128 VGPR
// of w_hh fragments (small enough that the compiler keeps them resident).
// h exchange: relaxed agent-scope atomics (sc1: write-through / L2-bypass to the
// coherent Infinity Cache) -> no threadfence, no L2 writeback/invalidate per step.
// Barrier: relaxed fetch_add + relaxed spin; __syncthreads' implied vmcnt(0) drains
// the write-through h stores before arrival.
__global__ __launch_bounds__(512, 1) void lstm_persist(
    const u16* __restrict__ w_hh,        // [2][2048][512]
    const u16* __restrict__ xgT,         // [2][2048][16384]  col = t*64+b
    u16* __restrict__ h_all,             // [256*64][1024]
    unsigned* __restrict__ bar)          // [2] counters, 256B apart
{
    __shared__ v4f redbuf[16 * 64];      // [nf*4+G][lane] partial sums from kh=1 (16KB)
    const int bx = blockIdx.x;
    const int d = bx >> 5, cg = bx & 31;
    const int tid = threadIdx.x;
    const int lane = tid & 63;
    const int nf = (tid >> 6) & 3, kh = tid >> 8;
    const int lrow = lane & 15, lk = lane >> 4;
    const int b = nf * 16 + lrow;        // this lane's batch column

    // ---- preload A fragments for this wave's K-half: a[G][q], kk = kh*8+q ----
    v8s a[4][8];
    #pragma unroll
    for (int G = 0; G < 4; ++G) {
        const u16* wrow = w_hh + ((size_t)d * G4 + G * HH + cg * 16 + lrow) * HH
                        + kh * 256 + lk * 8;
        #pragma unroll
        for (int q = 0; q < 8; ++q)
            a[G][q] = *reinterpret_cast<const v8s*>(wrow + q * 32);
    }

    float c[4] = {0.f, 0.f, 0.f, 0.f};
    float xg[4][4];
    unsigned* cnt = bar + d * 64;

    // xg for step 0 (kh==0 waves own the elementwise phase)
    {
        const int t0 = d ? (TT - 1) : 0;
        if (kh == 0) {
            const u16* xgb = xgT + (size_t)d * G4 * MTB + (size_t)t0 * BB + b;
            #pragma unroll
            for (int G = 0; G < 4; ++G)
                #pragma unroll
                for (int r = 0; r < 4; ++r)
                    xg[G][r] = bf2f(xgb[(size_t)(G * HH + cg * 16 + lk * 4 + r) * MTB]);
        }
    }

    for (int s = 0; s < TT; ++s) {
        const int t = d ? (TT - 1 - s) : s;

        // prefetch next step's xg early: latency hides under MFMA phase
        float xgn[4][4];
        const bool pf = (kh == 0) && (s + 1 < TT);
        if (pf) {
            const int tn = d ? (TT - 2 - s) : (s + 1);
            const u16* xgb = xgT + (size_t)d * G4 * MTB + (size_t)tn * BB + b;
            #pragma unroll
            for (int G = 0; G < 4; ++G)
                #pragma unroll
                for (int r = 0; r < 4; ++r)
                    xgn[G][r] = bf2f(xgb[(size_t)(G * HH + cg * 16 + lk * 4 + r) * MTB]);
        }

        v4f acc[4] = {};
        if (s > 0) {
            const int tprev = d ? (t + 1) : (t - 1);
            // B-fragments direct from IC (relaxed agent = sc1, bypasses stale L1/L2)
            const u16* hp = h_all + ((size_t)tprev * BB + b) * 1024 + d * HH
                          + kh * 256 + lk * 8;
            #pragma unroll
            for (int q = 0; q < 8; ++q) {
                union { unsigned long long w[2]; v8s v; } u;
                const u16* p = hp + q * 32;
                u.w[0] = __hip_atomic_load((const unsigned long long*)p,
                                           __ATOMIC_RELAXED, __HIP_MEMORY_SCOPE_AGENT);
                u.w[1] = __hip_atomic_load((const unsigned long long*)(p + 4),
                                           __ATOMIC_RELAXED, __HIP_MEMORY_SCOPE_AGENT);
                #pragma unroll
                for (int G = 0; G < 4; ++G)
                    acc[G] = __builtin_amdgcn_mfma_f32_16x16x32_bf16(a[G][q], u.v, acc[G], 0, 0, 0);
            }
            if (kh == 1) {
                #pragma unroll
                for (int G = 0; G < 4; ++G)
                    redbuf[(nf * 4 + G) * 64 + lane] = acc[G];
            }
        }
        __syncthreads();                      // (1) partials visible
        if (kh == 0) {
            ushort4 hout;
            #pragma unroll
            for (int G = 0; G < 4; ++G)
                if (s > 0) acc[G] += redbuf[(nf * 4 + G) * 64 + lane];
            #pragma unroll
            for (int r = 0; r < 4; ++r) {
                float pi = acc[0][r] + xg[0][r];
                float pfv = acc[1][r] + xg[1][r];
                float pg = acc[2][r] + xg[2][r];
                float po = acc[3][r] + xg[3][r];
                float iv = sigm(pi), fv = sigm(pfv), gv = tanh_(pg), ov = sigm(po);
                float cc = fv * c[r] + iv * gv;
                c[r] = cc;
                ((u16*)&hout)[r] = f2bf(ov * tanh_(cc));
            }
            // h[t][b][d*512 + cg*16 + lk*4 .. +3]: write-through store (agent-visible)
            union { ushort4 v; unsigned long long q; } hu; hu.v = hout;
            unsigned long long* hptr = (unsigned long long*)(
                h_all + ((size_t)t * BB + b) * 1024 + d * HH + cg * 16 + lk * 4);
            __hip_atomic_store(hptr, hu.q, __ATOMIC_RELAXED, __HIP_MEMORY_SCOPE_AGENT);
            if (pf) {
                #pragma unroll
                for (int G = 0; G < 4; ++G)
                    #pragma unroll
                    for (int r = 0; r < 4; ++r)
                        xg[G][r] = xgn[G][r];
            }
        }
        // ---- grid barrier among this dir's 32 blocks (fence-free) ----
        __syncthreads();                      // (2) drains all threads' h stores
        if (tid == 0) {
            __hip_atomic_fetch_add(cnt, 1u, __ATOMIC_RELAXED, __HIP_MEMORY_SCOPE_AGENT);
            const unsigned target = 32u * (unsigned)(s + 1);
            while (__hip_atomic_load(cnt, __ATOMIC_RELAXED, __HIP_MEMORY_SCOPE_AGENT) < target)
                __builtin_amdgcn_s_sleep(1);
        }
        __syncthreads();                      // (3) release whole block
    }
}

extern "C" void kernel_launch(void* const* d_in, const int* in_sizes, int n_in,
                              void* d_out, int out_size, void* d_ws, size_t ws_size,
                              hipStream_t stream) {
    const float* x    = (const float*)d_in[0];
    const float* wihf = (const float*)d_in[1];
    const float* whhf = (const float*)d_in[2];
    const float* bihf = (const float*)d_in[3];
    const float* bhhf = (const float*)d_in[4];
    const float* wihb = (const float*)d_in[5];
    const float* whhb = (const float*)d_in[6];
    const float* bihb = (const float*)d_in[7];
    const float* bhhb = (const float*)d_in[8];
    const float* fcw  = (const float*)d_in[9];
    const float* fcb  = (const float*)d_in[10];

    char* ws = (char*)d_ws;
    size_t off = 0;
    auto alloc = [&](size_t bytes) {
        off = (off + 255) & ~(size_t)255;
        char* p = ws + off; off += bytes; return p;
    };
    u16* x_bf    = (u16*)alloc((size_t)MTB * 512 * 2);        // 16.8 MB
    u16* wih_bf  = (u16*)alloc((size_t)2 * G4 * 512 * 2);     // 4.2 MB
    u16* whh_bf  = (u16*)alloc((size_t)2 * G4 * 512 * 2);     // 4.2 MB
    u16* fcw_bf  = (u16*)alloc((size_t)512 * 1024 * 2);       // 1.0 MB
    u16* xgT     = (u16*)alloc((size_t)2 * G4 * MTB * 2);     // 134.2 MB
    u16* h_all   = (u16*)alloc((size_t)MTB * 1024 * 2);       // 33.6 MB
    unsigned* bar = (unsigned*)alloc(512);                    // barrier counters
    (void)ws_size;

    // ---- convert inputs to bf16 ----
    cvt_bf16<<<1024, 256, 0, stream>>>(x, x_bf, MTB * 512);
    cvt_bf16<<<256, 256, 0, stream>>>(wihf, wih_bf, G4 * 512);
    cvt_bf16<<<256, 256, 0, stream>>>(wihb, wih_bf + (size_t)G4 * 512, G4 * 512);
    cvt_bf16<<<256, 256, 0, stream>>>(whhf, whh_bf, G4 * 512);
    cvt_bf16<<<256, 256, 0, stream>>>(whhb, whh_bf + (size_t)G4 * 512, G4 * 512);
    cvt_bf16<<<128, 256, 0, stream>>>(fcw, fcw_bf, 512 * 1024);

    // ---- phase 1: xgT[d] = w_ih[d] @ x^T + (b_ih + b_hh), bf16 out, gate-major ----
    gemm_bt<true, true><<<dim3(MTB / 128, G4 / 128), 256, 0, stream>>>(
        wih_bf, x_bf, xgT, bihf, bhhf, G4, MTB, 512);
    gemm_bt<true, true><<<dim3(MTB / 128, G4 / 128), 256, 0, stream>>>(
        wih_bf + (size_t)G4 * 512, x_bf, xgT + (size_t)G4 * MTB, bihb, bhhb, G4, MTB, 512);

    // ---- phase 2: persistent recurrence, fence-free software barrier ----
    hipMemsetAsync(bar, 0, 512, stream);
    lstm_persist<<<64, 512, 0, stream>>>(whh_bf, xgT, h_all, bar);

    // ---- phase 3: out = h_all @ fc_w^T + fc_b, fp32 out ----
    gemm_bt<false, false><<<dim3(512 / 128, MTB / 128), 256, 0, stream>>>(
        h_all, fcw_bf, d_out, fcb, nullptr, MTB, 512, 1024);
}